// Round 13
// baseline (1215.944 us; speedup 1.0000x reference)
//
#include <hip/hip_runtime.h>
#include <stdint.h>

typedef __attribute__((ext_vector_type(4))) float f32x4;
typedef __attribute__((ext_vector_type(8))) __bf16 bf16x8;

__device__ __forceinline__ ushort f2bf(float f) {
  union { float f; uint32_t u; } v; v.f = f;
  uint32_t r = v.u + 0x7fffu + ((v.u >> 16) & 1u);
  return (ushort)(r >> 16);
}
__device__ __forceinline__ float bf2f(uint32_t h) {
  union { uint32_t u; float f; } v; v.u = h << 16;
  return v.f;
}

// async global->LDS, 16B/lane; LDS dest is wave-uniform base + lane*16.
__device__ __forceinline__ void gload16(const void* g, const void* l) {
  __builtin_amdgcn_global_load_lds(
      (const __attribute__((address_space(1))) void*)(uintptr_t)g,
      (__attribute__((address_space(3))) void*)(uint32_t)(uintptr_t)l,
      16, 0, 0);
}

// ---------------------------------------------------------------------------
// Pipelined GEMM (r9 core, RING-2): C(M,N) = A(M,K)*B^T(N,K), batched bz.
// 256x256 tile, BK=32, 512 threads (8 waves 2Mx4N), ring-2 LDS (64KB ->
// 2 blocks/CU; VGPR ~100 <= 128 so HW occupancy doubles vs r9's 96KB ring-3).
// Per K-tile: P1 {vmcnt(1) -> BAR -> stage A0,B0(T+1) -> read A-mh0 + B ->
// setprio 16 MFMA}; P2 {vmcnt(2|0) -> BAR -> stage B1,A1(T+1) -> read A-mh1
// -> 16 MFMA}.  Stage-after-barrier: slot^1's readers (prev tile, both
// phases) retired before this barrier (reads complete before their MFMA,
// which precedes the barrier in program order) -> race-free.
// Ledger: P1 entry outstanding = 4 (tile T) -> vmcnt(1) confirms A0,B0,B1;
// P2 entry = 3 (A1(T) + A0,B0(T+1)) -> vmcnt(2) confirms A1(T). Tail: 1|0.
// Chunk swizzle both-sides (conflicts=0, coalescing kept).
// SWAPPED MFMA OPERANDS (r9-proven): per-thread j = 4 consecutive COLUMNS
// -> ushort4/float4 stores.  Mrow(m)=by*256+wr*128+(m>>2)*64+(m&3)*16+fr;
// Ncol(n)=bx*256+wc*64+n*16+fq*4+j.
// EPI 0: bf16 relu(acc+bias) (gating)      EPI 2: bf16 gate*relu(acc+bias)
// EPI 3: fused LoRA fp32                   EPI 4: fp32 acc (split-K partials)
// ---------------------------------------------------------------------------
template<int EPI, int COL>
__global__ __launch_bounds__(512, 1)
void gemm256p(const ushort* __restrict__ A, const ushort* __restrict__ Bt,
              const float* __restrict__ bias, const float* __restrict__ bias2,
              void* __restrict__ outp,
              int K, int lda, int ldb, int ldo,
              size_t aStride, size_t bStride, int biasStride, size_t oStride,
              const float* __restrict__ gates)
{
  __shared__ __attribute__((aligned(16))) char smem[2 * 32768]; // 64 KB

  const int bx = COL ? blockIdx.y : blockIdx.x;
  const int by = COL ? blockIdx.x : blockIdx.y;
  const int eb = blockIdx.z;

  const int t    = threadIdx.x;
  const int lane = t & 63;
  const int wid  = t >> 6;
  const int wr   = wid >> 2, wc = wid & 3;   // 2x4 waves; wave C = 128x64
  const int fr   = lane & 15, fq = lane >> 4;

  // staging sources (16B-chunk permuted within each row's 64B segment)
  const int r  = t >> 2;
  const int jc = (t & 3) ^ ((t >> 3) & 3);
  const ushort* Ae = A  + aStride * eb;
  const ushort* Be = Bt + bStride * eb;
  const ushort* sA0 = Ae + (size_t)(by * 256 + (r >> 6) * 128 +   0 + (r & 63)) * lda + jc * 8;
  const ushort* sA1 = Ae + (size_t)(by * 256 + (r >> 6) * 128 +  64 + (r & 63)) * lda + jc * 8;
  const ushort* sB0 = Be + (size_t)(bx * 256 +   0 + r) * ldb + jc * 8;
  const ushort* sB1 = Be + (size_t)(bx * 256 + 128 + r) * ldb + jc * 8;
  const int dT = t * 16;

  // ds_read bases (swizzled chunk select)
  const int swz  = (fq ^ ((fr >> 1) & 3)) * 16;
  const int aOff = (wr * 64 + fr) * 64 + swz;          // + mh*8192 + m*1024
  const int bOff = 16384 + (wc * 64 + fr) * 64 + swz;  // + n*1024

  f32x4 acc[8][4];
#pragma unroll
  for (int m = 0; m < 8; ++m)
#pragma unroll
    for (int n = 0; n < 4; ++n) acc[m][n] = (f32x4){0.f, 0.f, 0.f, 0.f};

  const int NT = K >> 5;

  // prologue: tile 0 into slot 0 (issue order: A0,B0,B1,A1)
  {
    char* d = smem;
    gload16(sA0, d + dT);
    gload16(sB0, d + 16384 + dT);
    gload16(sB1, d + 24576 + dT);
    gload16(sA1, d + 8192 + dT);
  }

  for (int T = 0; T < NT; ++T) {
    const char* base = smem + (T & 1) * 32768;
    char* d = smem + ((T & 1) ^ 1) * 32768;
    const bool pf = (T + 1 < NT);
    const int ko = (T + 1) * 32;

    // ---- P1: confirm A0,B0,B1 of T; stage A0,B0 of T+1; compute mh0 ----
    asm volatile("s_waitcnt vmcnt(1)" ::: "memory");
    __builtin_amdgcn_s_barrier();
    if (pf) { gload16(sA0 + ko, d + dT); gload16(sB0 + ko, d + 16384 + dT); }

    bf16x8 af[4], bf[4];
#pragma unroll
    for (int m = 0; m < 4; ++m) af[m] = *(const bf16x8*)(base + aOff + m * 1024);
#pragma unroll
    for (int n = 0; n < 4; ++n) bf[n] = *(const bf16x8*)(base + bOff + n * 1024);

    __builtin_amdgcn_s_setprio(1);
#pragma unroll
    for (int m = 0; m < 4; ++m)
#pragma unroll
      for (int n = 0; n < 4; ++n)
        acc[m][n] = __builtin_amdgcn_mfma_f32_16x16x32_bf16(bf[n], af[m], acc[m][n], 0, 0, 0);
    __builtin_amdgcn_s_setprio(0);

    // ---- P2: confirm A1 of T; stage B1,A1 of T+1; compute mh1 ----
    if (pf) asm volatile("s_waitcnt vmcnt(2)" ::: "memory");
    else    asm volatile("s_waitcnt vmcnt(0)" ::: "memory");
    __builtin_amdgcn_s_barrier();
    if (pf) { gload16(sB1 + ko, d + 24576 + dT); gload16(sA1 + ko, d + 8192 + dT); }

#pragma unroll
    for (int m = 0; m < 4; ++m) af[m] = *(const bf16x8*)(base + 8192 + aOff + m * 1024);
    __builtin_amdgcn_s_setprio(1);
#pragma unroll
    for (int m = 0; m < 4; ++m)
#pragma unroll
      for (int n = 0; n < 4; ++n)
        acc[4 + m][n] = __builtin_amdgcn_mfma_f32_16x16x32_bf16(bf[n], af[m], acc[4 + m][n], 0, 0, 0);
    __builtin_amdgcn_s_setprio(0);
  }

  // epilogue (swapped-operand mapping; j-contiguous columns)
  const int grow0 = by * 256 + wr * 128 + fr;
  const int gcol0 = bx * 256 + wc * 64 + fq * 4;

  if (EPI == 0) {
    ushort* oo = (ushort*)outp + oStride * eb;
    const float* bb = bias + (size_t)biasStride * eb;
#pragma unroll
    for (int m = 0; m < 8; ++m) {
      const int Mr = grow0 + (m >> 2) * 64 + (m & 3) * 16;
#pragma unroll
      for (int n = 0; n < 4; ++n) {
        const int Nc = gcol0 + n * 16;
        const f32x4 bv = *(const f32x4*)&bb[Nc];
        ushort4 o4;
        float v0 = acc[m][n][0] + bv[0]; float v1 = acc[m][n][1] + bv[1];
        float v2 = acc[m][n][2] + bv[2]; float v3 = acc[m][n][3] + bv[3];
        o4.x = f2bf(v0 > 0.f ? v0 : 0.f); o4.y = f2bf(v1 > 0.f ? v1 : 0.f);
        o4.z = f2bf(v2 > 0.f ? v2 : 0.f); o4.w = f2bf(v3 > 0.f ? v3 : 0.f);
        *(ushort4*)&oo[(size_t)Mr * ldo + Nc] = o4;
      }
    }
  } else if (EPI == 2) { // gated relu bf16 (expert-1 into h)
    ushort* oo = (ushort*)outp + oStride * eb;   // column offset per expert
    const float* bb = bias + (size_t)biasStride * eb;
#pragma unroll
    for (int m = 0; m < 8; ++m) {
      const int Mr = grow0 + (m >> 2) * 64 + (m & 3) * 16;
      const float g = gates[(size_t)Mr * 16 + eb];
#pragma unroll
      for (int n = 0; n < 4; ++n) {
        const int Nc = gcol0 + n * 16;
        const f32x4 bv = *(const f32x4*)&bb[Nc];
        ushort4 o4;
        float v0 = acc[m][n][0] + bv[0]; float v1 = acc[m][n][1] + bv[1];
        float v2 = acc[m][n][2] + bv[2]; float v3 = acc[m][n][3] + bv[3];
        o4.x = f2bf(v0 > 0.f ? g * v0 : 0.f); o4.y = f2bf(v1 > 0.f ? g * v1 : 0.f);
        o4.z = f2bf(v2 > 0.f ? g * v2 : 0.f); o4.w = f2bf(v3 > 0.f ? g * v3 : 0.f);
        *(ushort4*)&oo[(size_t)Mr * ldo + Nc] = o4;
      }
    }
  } else if (EPI == 4) { // plain fp32 store (e2 split-K partials)
    float* oo = (float*)outp + oStride * eb;
#pragma unroll
    for (int m = 0; m < 8; ++m) {
      const int Mr = grow0 + (m >> 2) * 64 + (m & 3) * 16;
#pragma unroll
      for (int n = 0; n < 4; ++n)
        *(f32x4*)&oo[(size_t)Mr * ldo + gcol0 + n * 16] = acc[m][n];
    }
  } else { // EPI 3: fused LoRA heads (fp32, float4 stores)
    const bool second = (gcol0 >= ldo);
    const float* bp = second ? bias2 : bias;
    float* oo = (float*)outp + (second ? oStride : 0);
    const int cb = second ? ldo : 0;
#pragma unroll
    for (int m = 0; m < 8; ++m) {
      const int Mr = grow0 + (m >> 2) * 64 + (m & 3) * 16;
#pragma unroll
      for (int n = 0; n < 4; ++n) {
        const int Nc = gcol0 + n * 16 - cb;
        const f32x4 bv = *(const f32x4*)&bp[Nc];
        *(f32x4*)&oo[(size_t)Mr * ldo + Nc] = acc[m][n] + bv;
      }
    }
  }
}

// ---------------------------------------------------------------------------
// transpose + cvt: in (K,N) f32 -> out (N,K) bf16. 64x64 tiles, vectorized.
// ---------------------------------------------------------------------------
__global__ __launch_bounds__(256)
void transpose_cvt(const float* __restrict__ in, ushort* __restrict__ out,
                   int K, int N, size_t inStride, size_t outStride)
{
  __shared__ float tile[64][65];
  const float* I = in + inStride * blockIdx.z;
  ushort* O = out + outStride * blockIdx.z;
  const int n0 = blockIdx.x * 64, k0 = blockIdx.y * 64;
  const int t = threadIdx.x;
  const int r = t >> 4, cv = (t & 15) * 4;
#pragma unroll
  for (int pp = 0; pp < 4; ++pp) {
    const int kr = r + pp * 16;
    const float4 v = *(const float4*)&I[(size_t)(k0 + kr) * N + (n0 + cv)];
    tile[kr][cv] = v.x; tile[kr][cv + 1] = v.y; tile[kr][cv + 2] = v.z; tile[kr][cv + 3] = v.w;
  }
  __syncthreads();
#pragma unroll
  for (int pp = 0; pp < 4; ++pp) {
    const int nr = r + pp * 16;
    ushort4 o4;
    o4.x = f2bf(tile[cv + 0][nr]); o4.y = f2bf(tile[cv + 1][nr]);
    o4.z = f2bf(tile[cv + 2][nr]); o4.w = f2bf(tile[cv + 3][nr]);
    *(ushort4*)&O[(size_t)(n0 + nr) * K + (k0 + cv)] = o4;
  }
}

// x = concat(s, c) as bf16, row stride 1536. 8 elems/thread.
__global__ __launch_bounds__(256)
void build_x(const float* __restrict__ s, const float* __restrict__ c, ushort* __restrict__ x)
{
  const size_t i = (size_t)blockIdx.x * 256 + threadIdx.x;
  const size_t b = i / 192;
  const int col  = (int)(i % 192) * 8;
  const float* src = (col < 1024) ? (s + b * 1024 + col) : (c + b * 512 + (col - 1024));
  const float4 v0 = ((const float4*)src)[0];
  const float4 v1 = ((const float4*)src)[1];
  uint4 o;
  o.x = f2bf(v0.x) | ((uint32_t)f2bf(v0.y) << 16);
  o.y = f2bf(v0.z) | ((uint32_t)f2bf(v0.w) << 16);
  o.z = f2bf(v1.x) | ((uint32_t)f2bf(v1.y) << 16);
  o.w = f2bf(v1.z) | ((uint32_t)f2bf(v1.w) << 16);
  *(uint4*)(x + i * 8) = o;
}

// zb = bf16( sum_{s=0..15} zsplit[s] + gates @ be2 ), 4 floats/thread
__global__ __launch_bounds__(256)
void reduce_z16(const float* __restrict__ zs, const float* __restrict__ gates,
                const float* __restrict__ be2, ushort* __restrict__ zb)
{
  const size_t i = ((size_t)blockIdx.x * 256 + threadIdx.x) * 4;
  const size_t S = (size_t)4096 * 512;
  const int rrow = (int)(i >> 9);
  const int ccol = (int)(i & 511);
  float4 sv = {0.f, 0.f, 0.f, 0.f};
#pragma unroll
  for (int p = 0; p < 16; ++p) {
    const float4 v = *(const float4*)(zs + (size_t)p * S + i);
    sv.x += v.x; sv.y += v.y; sv.z += v.z; sv.w += v.w;
  }
#pragma unroll
  for (int e = 0; e < 16; ++e) {
    const float ge = gates[(size_t)rrow * 16 + e];
    const float4 bv = *(const float4*)(be2 + (size_t)e * 512 + ccol);
    sv.x += ge * bv.x; sv.y += ge * bv.y; sv.z += ge * bv.z; sv.w += ge * bv.w;
  }
  ushort4 o4;
  o4.x = f2bf(sv.x); o4.y = f2bf(sv.y); o4.z = f2bf(sv.z); o4.w = f2bf(sv.w);
  *(ushort4*)(zb + i) = o4;
}

// gating second layer + softmax: one wave per row.
__global__ __launch_bounds__(256)
void gating2_softmax(const ushort* __restrict__ hg, const float* __restrict__ Wg2,
                     const float* __restrict__ bg2, float* __restrict__ gates)
{
  const int row  = (int)((blockIdx.x * 256 + threadIdx.x) >> 6);
  const int lane = threadIdx.x & 63;
  float acc[16];
#pragma unroll
  for (int e = 0; e < 16; ++e) acc[e] = 0.f;
  const ushort* hrow = hg + (size_t)row * 2048;
#pragma unroll
  for (int it = 0; it < 4; ++it) {
    const int kb = it * 512 + lane * 8;
    const uint4 pk = *(const uint4*)(hrow + kb);
    float hv[8] = { bf2f(pk.x & 0xffffu), bf2f(pk.x >> 16),
                    bf2f(pk.y & 0xffffu), bf2f(pk.y >> 16),
                    bf2f(pk.z & 0xffffu), bf2f(pk.z >> 16),
                    bf2f(pk.w & 0xffffu), bf2f(pk.w >> 16) };
#pragma unroll
    for (int j = 0; j < 8; ++j) {
      const float* wrow = Wg2 + (size_t)(kb + j) * 16;
#pragma unroll
      for (int e = 0; e < 16; ++e) acc[e] += hv[j] * wrow[e];
    }
  }
#pragma unroll
  for (int e = 0; e < 16; ++e) {
#pragma unroll
    for (int off = 32; off > 0; off >>= 1) acc[e] += __shfl_xor(acc[e], off);
    acc[e] += bg2[e];
  }
  float mx = acc[0];
#pragma unroll
  for (int e = 1; e < 16; ++e) mx = fmaxf(mx, acc[e]);
  float sum = 0.f;
#pragma unroll
  for (int e = 0; e < 16; ++e) { acc[e] = __expf(acc[e] - mx); sum += acc[e]; }
  const float inv = 1.f / sum;
  if (lane == 0) {
#pragma unroll
    for (int e = 0; e < 16; ++e) gates[(size_t)row * 16 + e] = acc[e] * inv;
  }
}

// ---------------------------------------------------------------------------
extern "C" void kernel_launch(void* const* d_in, const int* in_sizes, int n_in,
                              void* d_out, int out_size, void* d_ws, size_t ws_size,
                              hipStream_t stream)
{
  (void)in_sizes; (void)n_in; (void)out_size; (void)ws_size;
  const float* s   = (const float*)d_in[0];
  const float* c   = (const float*)d_in[1];
  const float* Wg1 = (const float*)d_in[2];
  const float* bg1 = (const float*)d_in[3];
  const float* Wg2 = (const float*)d_in[4];
  const float* bg2 = (const float*)d_in[5];
  const float* We1 = (const float*)d_in[6];
  const float* be1 = (const float*)d_in[7];
  const float* We2 = (const float*)d_in[8];
  const float* be2 = (const float*)d_in[9];
  const float* WA  = (const float*)d_in[10];
  const float* bA  = (const float*)d_in[11];
  const float* WB  = (const float*)d_in[12];
  const float* bB  = (const float*)d_in[13];
  float* out = (float*)d_out;

  char* ws = (char*)d_ws;
  size_t off = 0;
  auto alloc = [&](size_t bytes) {
    void* p = ws + off; off += (bytes + 255) & ~(size_t)255; return p;
  };
  ushort* x      = (ushort*)alloc((size_t)4096 * 1536 * 2);      // 12.6 MB
  ushort* We1T   = (ushort*)alloc((size_t)16 * 2048 * 1536 * 2); // 100.7 MB
  ushort* We2cat = (ushort*)alloc((size_t)512 * 32768 * 2);      // 33.6 MB
  ushort* WABT   = (ushort*)alloc((size_t)32768 * 512 * 2);      // 33.6 MB
  float*  gates  = (float*)alloc((size_t)4096 * 16 * 4);
  float*  zsplit = (float*)alloc((size_t)16 * 4096 * 512 * 4);   // 134.2 MB
  ushort* zb     = (ushort*)alloc((size_t)4096 * 512 * 2);       //  4.2 MB
  ushort* h      = (ushort*)alloc((size_t)4096 * 32768 * 2);     // 268.4 MB
  // aliases inside h (dead before h is written):
  ushort* Wg1T = h;                                              // 4.2 MB
  ushort* hg   = (ushort*)((char*)h + (size_t)2048 * 1024 * 2);  // 16.8 MB

  const size_t S_We1 = (size_t)2048 * 1536;
  const size_t S_We2 = (size_t)512 * 2048;
  const size_t S_z   = (size_t)4096 * 512;

  build_x<<<3072, 256, 0, stream>>>(s, c, x);
  transpose_cvt<<<dim3(32, 16, 1),  256, 0, stream>>>(Wg1, Wg1T, 1024, 2048, 0, 0);
  transpose_cvt<<<dim3(32, 24, 16), 256, 0, stream>>>(We1, We1T, 1536, 2048, S_We1, S_We1);
  // We2cat: [512 n][32768 k], per-expert k-offset 2048
  transpose_cvt<<<dim3(8, 32, 16),  256, 0, stream>>>(We2, We2cat, 32768, 512, S_We2, 2048);
  transpose_cvt<<<dim3(256, 8, 1),  256, 0, stream>>>(WA, WABT, 512, 16384, 0, 0);
  transpose_cvt<<<dim3(256, 8, 1),  256, 0, stream>>>(WB, WABT + (size_t)16384 * 512, 512, 16384, 0, 0);

  // gating: hg = relu(s @ Wg1 + bg1), then gates = softmax(hg @ Wg2 + bg2)
  gemm256p<0, 1><<<dim3(16, 8, 1), 512, 0, stream>>>(x, Wg1T, bg1, nullptr, hg,
      1024, 1536, 1024, 2048, 0, 0, 0, 0, nullptr);
  gating2_softmax<<<1024, 256, 0, stream>>>(hg, Wg2, bg2, gates);

  // expert-1 (all 16, one dispatch): h[r, e*2048+c] = g[r,e]*relu(x@We1[e]^T + be1[e])
  gemm256p<2, 1><<<dim3(16, 8, 16), 512, 0, stream>>>(x, We1T, be1, nullptr, h,
      1536, 1536, 1536, 32768, 0, S_We1, 2048, 2048, gates);

  // expert-2 as ONE GEMM K=32768, split-K x16 into zsplit (fp32 float4 stores)
  gemm256p<4, 0><<<dim3(2, 16, 16), 512, 0, stream>>>(h, We2cat, be2, nullptr, zsplit,
      2048, 32768, 32768, 512, 2048, 2048, 0, S_z, nullptr);

  // zb = bf16( sum_s zsplit[s] + gates @ be2 )
  reduce_z16<<<2048, 256, 0, stream>>>(zsplit, gates, be2, zb);

  // fused LoRA heads: C = zb @ [WA; WB]^T
  gemm256p<3, 1><<<dim3(16, 128, 1), 512, 0, stream>>>(zb, WABT, bA, bB, out,
      512, 512, 512, 16384, 0, 0, 0, (size_t)4096 * 16384, nullptr);
}

// Round 14
// 1094.129 us; speedup vs baseline: 1.1113x; 1.1113x over previous
//
#include <hip/hip_runtime.h>
#include <stdint.h>

typedef __attribute__((ext_vector_type(4))) float f32x4;
typedef __attribute__((ext_vector_type(8))) __bf16 bf16x8;

__device__ __forceinline__ ushort f2bf(float f) {
  union { float f; uint32_t u; } v; v.f = f;
  uint32_t r = v.u + 0x7fffu + ((v.u >> 16) & 1u);
  return (ushort)(r >> 16);
}
__device__ __forceinline__ float bf2f(uint32_t h) {
  union { uint32_t u; float f; } v; v.u = h << 16;
  return v.f;
}

// async global->LDS, 16B/lane; LDS dest is wave-uniform base + lane*16.
__device__ __forceinline__ void gload16(const void* g, const void* l) {
  __builtin_amdgcn_global_load_lds(
      (const __attribute__((address_space(1))) void*)(uintptr_t)g,
      (__attribute__((address_space(3))) void*)(uint32_t)(uintptr_t)l,
      16, 0, 0);
}

// ---------------------------------------------------------------------------
// Pipelined GEMM (r9-proven core, best measured: e1 845 TF): C = A * B^T,
// batched over bz. 256x256 tile, BK=32, 512 threads (8 waves 2Mx4N),
// ring-3 LDS (96KB), counted vmcnt + raw barriers, chunk swizzle both-sides
// (conflicts=0, coalescing preserved).
// SWAPPED MFMA OPERANDS: acc[m][n] = mfma(bf[n], af[m], acc) so per-thread
// j-elements are 4 CONSECUTIVE COLUMNS -> ushort4/float4 epilogue stores.
//   Mrow(m) = by*256 + wr*128 + (m>>2)*64 + (m&3)*16 + fr
//   Ncol(n) = bx*256 + wc*64  + n*16 + fq*4 + j  (j = 0..3 contiguous)
// EPI 0: out bf16 = relu(acc + bias[n]); out += oStride*eb   (gating)
// EPI 2: out bf16 = gates[Mrow*16+eb] * relu(acc + bias[n]); col off oStride*eb
// EPI 3: fused LoRA fp32: cols < ldo -> out+bias, else out+oStride+bias2
// EPI 4: out fp32 = acc (no bias); out += oStride*eb          (e2 split-K)
// ---------------------------------------------------------------------------
template<int EPI, int COL>
__global__ __launch_bounds__(512, 1)
void gemm256p(const ushort* __restrict__ A, const ushort* __restrict__ Bt,
              const float* __restrict__ bias, const float* __restrict__ bias2,
              void* __restrict__ outp,
              int K, int lda, int ldb, int ldo,
              size_t aStride, size_t bStride, int biasStride, size_t oStride,
              const float* __restrict__ gates)
{
  __shared__ __attribute__((aligned(16))) char smem[3 * 32768];

  const int bx = COL ? blockIdx.y : blockIdx.x;
  const int by = COL ? blockIdx.x : blockIdx.y;
  const int eb = blockIdx.z;

  const int t    = threadIdx.x;
  const int lane = t & 63;
  const int wid  = t >> 6;
  const int wr   = wid >> 2, wc = wid & 3;   // 2x4 waves; wave C = 128x64
  const int fr   = lane & 15, fq = lane >> 4;

  // staging sources (16B-chunk permuted within each row's 64B segment)
  const int r  = t >> 2;
  const int jc = (t & 3) ^ ((t >> 3) & 3);
  const ushort* Ae = A  + aStride * eb;
  const ushort* Be = Bt + bStride * eb;
  const ushort* sA0 = Ae + (size_t)(by * 256 + (r >> 6) * 128 +   0 + (r & 63)) * lda + jc * 8;
  const ushort* sA1 = Ae + (size_t)(by * 256 + (r >> 6) * 128 +  64 + (r & 63)) * lda + jc * 8;
  const ushort* sB0 = Be + (size_t)(bx * 256 +   0 + r) * ldb + jc * 8;
  const ushort* sB1 = Be + (size_t)(bx * 256 + 128 + r) * ldb + jc * 8;
  const int dT = t * 16;

  // ds_read bases (swizzled chunk select)
  const int swz  = (fq ^ ((fr >> 1) & 3)) * 16;
  const int aOff = (wr * 64 + fr) * 64 + swz;          // + mh*8192 + m*1024
  const int bOff = 16384 + (wc * 64 + fr) * 64 + swz;  // + n*1024

  f32x4 acc[8][4];
#pragma unroll
  for (int m = 0; m < 8; ++m)
#pragma unroll
    for (int n = 0; n < 4; ++n) acc[m][n] = (f32x4){0.f, 0.f, 0.f, 0.f};

  const int NT = K >> 5;

  // prologue: tiles 0,1 (issue order per tile: A0,B0,B1,A1)
#pragma unroll
  for (int kt = 0; kt < 2; ++kt) {
    char* d = smem + kt * 32768;
    gload16(sA0 + kt * 32, d + dT);
    gload16(sB0 + kt * 32, d + 16384 + dT);
    gload16(sB1 + kt * 32, d + 24576 + dT);
    gload16(sA1 + kt * 32, d + 8192 + dT);
  }

  int sc = 0;
  for (int T = 0; T < NT; ++T) {
    const char* base = smem + sc * 32768;
    const int ssi = (sc + 2 >= 3) ? sc - 1 : sc + 2;
    char* d = smem + ssi * 32768;
    const bool pf = (T + 2 < NT);
    const int ko = (T + 2) * 32;

    // ---- phase 1 (mh=0) ----
    if (T < NT - 1) asm volatile("s_waitcnt vmcnt(5)" ::: "memory");
    else            asm volatile("s_waitcnt vmcnt(1)" ::: "memory");
    __builtin_amdgcn_s_barrier();
    if (pf) { gload16(sA0 + ko, d + dT); gload16(sB0 + ko, d + 16384 + dT); }

    bf16x8 af[4], bf[4];
#pragma unroll
    for (int m = 0; m < 4; ++m) af[m] = *(const bf16x8*)(base + aOff + m * 1024);
#pragma unroll
    for (int n = 0; n < 4; ++n) bf[n] = *(const bf16x8*)(base + bOff + n * 1024);

    __builtin_amdgcn_s_setprio(1);
#pragma unroll
    for (int m = 0; m < 4; ++m)
#pragma unroll
      for (int n = 0; n < 4; ++n)
        acc[m][n] = __builtin_amdgcn_mfma_f32_16x16x32_bf16(bf[n], af[m], acc[m][n], 0, 0, 0);
    __builtin_amdgcn_s_setprio(0);

    // ---- phase 2 (mh=1) ----
    if (T < NT - 2)       asm volatile("s_waitcnt vmcnt(6)" ::: "memory");
    else if (T == NT - 2) asm volatile("s_waitcnt vmcnt(4)" ::: "memory");
    else                  asm volatile("s_waitcnt vmcnt(0)" ::: "memory");
    __builtin_amdgcn_s_barrier();
    if (pf) { gload16(sB1 + ko, d + 24576 + dT); gload16(sA1 + ko, d + 8192 + dT); }

#pragma unroll
    for (int m = 0; m < 4; ++m) af[m] = *(const bf16x8*)(base + 8192 + aOff + m * 1024);
    __builtin_amdgcn_s_setprio(1);
#pragma unroll
    for (int m = 0; m < 4; ++m)
#pragma unroll
      for (int n = 0; n < 4; ++n)
        acc[4 + m][n] = __builtin_amdgcn_mfma_f32_16x16x32_bf16(bf[n], af[m], acc[4 + m][n], 0, 0, 0);
    __builtin_amdgcn_s_setprio(0);

    sc = (sc + 1 == 3) ? 0 : sc + 1;
  }

  // epilogue (swapped-operand mapping; j-contiguous columns)
  const int grow0 = by * 256 + wr * 128 + fr;
  const int gcol0 = bx * 256 + wc * 64 + fq * 4;

  if (EPI == 0) {
    ushort* oo = (ushort*)outp + oStride * eb;
    const float* bb = bias + (size_t)biasStride * eb;
#pragma unroll
    for (int m = 0; m < 8; ++m) {
      const int Mr = grow0 + (m >> 2) * 64 + (m & 3) * 16;
#pragma unroll
      for (int n = 0; n < 4; ++n) {
        const int Nc = gcol0 + n * 16;
        const f32x4 bv = *(const f32x4*)&bb[Nc];
        ushort4 o4;
        float v0 = acc[m][n][0] + bv[0]; float v1 = acc[m][n][1] + bv[1];
        float v2 = acc[m][n][2] + bv[2]; float v3 = acc[m][n][3] + bv[3];
        o4.x = f2bf(v0 > 0.f ? v0 : 0.f); o4.y = f2bf(v1 > 0.f ? v1 : 0.f);
        o4.z = f2bf(v2 > 0.f ? v2 : 0.f); o4.w = f2bf(v3 > 0.f ? v3 : 0.f);
        *(ushort4*)&oo[(size_t)Mr * ldo + Nc] = o4;
      }
    }
  } else if (EPI == 2) { // gated relu bf16 (expert-1 into h)
    ushort* oo = (ushort*)outp + oStride * eb;   // column offset per expert
    const float* bb = bias + (size_t)biasStride * eb;
#pragma unroll
    for (int m = 0; m < 8; ++m) {
      const int Mr = grow0 + (m >> 2) * 64 + (m & 3) * 16;
      const float g = gates[(size_t)Mr * 16 + eb];
#pragma unroll
      for (int n = 0; n < 4; ++n) {
        const int Nc = gcol0 + n * 16;
        const f32x4 bv = *(const f32x4*)&bb[Nc];
        ushort4 o4;
        float v0 = acc[m][n][0] + bv[0]; float v1 = acc[m][n][1] + bv[1];
        float v2 = acc[m][n][2] + bv[2]; float v3 = acc[m][n][3] + bv[3];
        o4.x = f2bf(v0 > 0.f ? g * v0 : 0.f); o4.y = f2bf(v1 > 0.f ? g * v1 : 0.f);
        o4.z = f2bf(v2 > 0.f ? g * v2 : 0.f); o4.w = f2bf(v3 > 0.f ? g * v3 : 0.f);
        *(ushort4*)&oo[(size_t)Mr * ldo + Nc] = o4;
      }
    }
  } else if (EPI == 4) { // plain fp32 store (e2 split-K partials)
    float* oo = (float*)outp + oStride * eb;
#pragma unroll
    for (int m = 0; m < 8; ++m) {
      const int Mr = grow0 + (m >> 2) * 64 + (m & 3) * 16;
#pragma unroll
      for (int n = 0; n < 4; ++n)
        *(f32x4*)&oo[(size_t)Mr * ldo + gcol0 + n * 16] = acc[m][n];
    }
  } else { // EPI 3: fused LoRA heads (fp32, float4 stores)
    const bool second = (gcol0 >= ldo);
    const float* bp = second ? bias2 : bias;
    float* oo = (float*)outp + (second ? oStride : 0);
    const int cb = second ? ldo : 0;
#pragma unroll
    for (int m = 0; m < 8; ++m) {
      const int Mr = grow0 + (m >> 2) * 64 + (m & 3) * 16;
#pragma unroll
      for (int n = 0; n < 4; ++n) {
        const int Nc = gcol0 + n * 16 - cb;
        const f32x4 bv = *(const f32x4*)&bp[Nc];
        *(f32x4*)&oo[(size_t)Mr * ldo + Nc] = acc[m][n] + bv;
      }
    }
  }
}

// ---------------------------------------------------------------------------
// transpose + cvt: in (K,N) f32 -> out (N,K) bf16. 64x64 tiles, vectorized.
// ---------------------------------------------------------------------------
__global__ __launch_bounds__(256)
void transpose_cvt(const float* __restrict__ in, ushort* __restrict__ out,
                   int K, int N, size_t inStride, size_t outStride)
{
  __shared__ float tile[64][65];
  const float* I = in + inStride * blockIdx.z;
  ushort* O = out + outStride * blockIdx.z;
  const int n0 = blockIdx.x * 64, k0 = blockIdx.y * 64;
  const int t = threadIdx.x;
  const int r = t >> 4, cv = (t & 15) * 4;
#pragma unroll
  for (int pp = 0; pp < 4; ++pp) {
    const int kr = r + pp * 16;
    const float4 v = *(const float4*)&I[(size_t)(k0 + kr) * N + (n0 + cv)];
    tile[kr][cv] = v.x; tile[kr][cv + 1] = v.y; tile[kr][cv + 2] = v.z; tile[kr][cv + 3] = v.w;
  }
  __syncthreads();
#pragma unroll
  for (int pp = 0; pp < 4; ++pp) {
    const int nr = r + pp * 16;
    ushort4 o4;
    o4.x = f2bf(tile[cv + 0][nr]); o4.y = f2bf(tile[cv + 1][nr]);
    o4.z = f2bf(tile[cv + 2][nr]); o4.w = f2bf(tile[cv + 3][nr]);
    *(ushort4*)&O[(size_t)(n0 + nr) * K + (k0 + cv)] = o4;
  }
}

// x = concat(s, c) as bf16, row stride 1536. 8 elems/thread.
__global__ __launch_bounds__(256)
void build_x(const float* __restrict__ s, const float* __restrict__ c, ushort* __restrict__ x)
{
  const size_t i = (size_t)blockIdx.x * 256 + threadIdx.x;
  const size_t b = i / 192;
  const int col  = (int)(i % 192) * 8;
  const float* src = (col < 1024) ? (s + b * 1024 + col) : (c + b * 512 + (col - 1024));
  const float4 v0 = ((const float4*)src)[0];
  const float4 v1 = ((const float4*)src)[1];
  uint4 o;
  o.x = f2bf(v0.x) | ((uint32_t)f2bf(v0.y) << 16);
  o.y = f2bf(v0.z) | ((uint32_t)f2bf(v0.w) << 16);
  o.z = f2bf(v1.x) | ((uint32_t)f2bf(v1.y) << 16);
  o.w = f2bf(v1.z) | ((uint32_t)f2bf(v1.w) << 16);
  *(uint4*)(x + i * 8) = o;
}

// zb = bf16( sum_{s=0..7} zsplit[s] + gates @ be2 ), 4 floats/thread
__global__ __launch_bounds__(256)
void reduce_z8(const float* __restrict__ zs, const float* __restrict__ gates,
               const float* __restrict__ be2, ushort* __restrict__ zb)
{
  const size_t i = ((size_t)blockIdx.x * 256 + threadIdx.x) * 4;
  const size_t S = (size_t)4096 * 512;
  const int rrow = (int)(i >> 9);
  const int ccol = (int)(i & 511);
  float4 sv = {0.f, 0.f, 0.f, 0.f};
#pragma unroll
  for (int p = 0; p < 8; ++p) {
    const float4 v = *(const float4*)(zs + (size_t)p * S + i);
    sv.x += v.x; sv.y += v.y; sv.z += v.z; sv.w += v.w;
  }
#pragma unroll
  for (int e = 0; e < 16; ++e) {
    const float ge = gates[(size_t)rrow * 16 + e];
    const float4 bv = *(const float4*)(be2 + (size_t)e * 512 + ccol);
    sv.x += ge * bv.x; sv.y += ge * bv.y; sv.z += ge * bv.z; sv.w += ge * bv.w;
  }
  ushort4 o4;
  o4.x = f2bf(sv.x); o4.y = f2bf(sv.y); o4.z = f2bf(sv.z); o4.w = f2bf(sv.w);
  *(ushort4*)(zb + i) = o4;
}

// gating second layer + softmax: one wave per row.
__global__ __launch_bounds__(256)
void gating2_softmax(const ushort* __restrict__ hg, const float* __restrict__ Wg2,
                     const float* __restrict__ bg2, float* __restrict__ gates)
{
  const int row  = (int)((blockIdx.x * 256 + threadIdx.x) >> 6);
  const int lane = threadIdx.x & 63;
  float acc[16];
#pragma unroll
  for (int e = 0; e < 16; ++e) acc[e] = 0.f;
  const ushort* hrow = hg + (size_t)row * 2048;
#pragma unroll
  for (int it = 0; it < 4; ++it) {
    const int kb = it * 512 + lane * 8;
    const uint4 pk = *(const uint4*)(hrow + kb);
    float hv[8] = { bf2f(pk.x & 0xffffu), bf2f(pk.x >> 16),
                    bf2f(pk.y & 0xffffu), bf2f(pk.y >> 16),
                    bf2f(pk.z & 0xffffu), bf2f(pk.z >> 16),
                    bf2f(pk.w & 0xffffu), bf2f(pk.w >> 16) };
#pragma unroll
    for (int j = 0; j < 8; ++j) {
      const float* wrow = Wg2 + (size_t)(kb + j) * 16;
#pragma unroll
      for (int e = 0; e < 16; ++e) acc[e] += hv[j] * wrow[e];
    }
  }
#pragma unroll
  for (int e = 0; e < 16; ++e) {
#pragma unroll
    for (int off = 32; off > 0; off >>= 1) acc[e] += __shfl_xor(acc[e], off);
    acc[e] += bg2[e];
  }
  float mx = acc[0];
#pragma unroll
  for (int e = 1; e < 16; ++e) mx = fmaxf(mx, acc[e]);
  float sum = 0.f;
#pragma unroll
  for (int e = 0; e < 16; ++e) { acc[e] = __expf(acc[e] - mx); sum += acc[e]; }
  const float inv = 1.f / sum;
  if (lane == 0) {
#pragma unroll
    for (int e = 0; e < 16; ++e) gates[(size_t)row * 16 + e] = acc[e] * inv;
  }
}

// ---------------------------------------------------------------------------
extern "C" void kernel_launch(void* const* d_in, const int* in_sizes, int n_in,
                              void* d_out, int out_size, void* d_ws, size_t ws_size,
                              hipStream_t stream)
{
  (void)in_sizes; (void)n_in; (void)out_size; (void)ws_size;
  const float* s   = (const float*)d_in[0];
  const float* c   = (const float*)d_in[1];
  const float* Wg1 = (const float*)d_in[2];
  const float* bg1 = (const float*)d_in[3];
  const float* Wg2 = (const float*)d_in[4];
  const float* bg2 = (const float*)d_in[5];
  const float* We1 = (const float*)d_in[6];
  const float* be1 = (const float*)d_in[7];
  const float* We2 = (const float*)d_in[8];
  const float* be2 = (const float*)d_in[9];
  const float* WA  = (const float*)d_in[10];
  const float* bA  = (const float*)d_in[11];
  const float* WB  = (const float*)d_in[12];
  const float* bB  = (const float*)d_in[13];
  float* out = (float*)d_out;

  char* ws = (char*)d_ws;
  size_t off = 0;
  auto alloc = [&](size_t bytes) {
    void* p = ws + off; off += (bytes + 255) & ~(size_t)255; return p;
  };
  ushort* x      = (ushort*)alloc((size_t)4096 * 1536 * 2);      // 12.6 MB
  ushort* We1T   = (ushort*)alloc((size_t)16 * 2048 * 1536 * 2); // 100.7 MB
  ushort* We2cat = (ushort*)alloc((size_t)512 * 32768 * 2);      // 33.6 MB
  ushort* WABT   = (ushort*)alloc((size_t)32768 * 512 * 2);      // 33.6 MB
  float*  gates  = (float*)alloc((size_t)4096 * 16 * 4);
  float*  zsplit = (float*)alloc((size_t)8 * 4096 * 512 * 4);    // 67.1 MB
  ushort* zb     = (ushort*)alloc((size_t)4096 * 512 * 2);       //  4.2 MB
  ushort* h      = (ushort*)alloc((size_t)4096 * 32768 * 2);     // 268.4 MB
  // aliases inside h (dead before h is written):
  ushort* Wg1T = h;                                              // 4.2 MB
  ushort* hg   = (ushort*)((char*)h + (size_t)2048 * 1024 * 2);  // 16.8 MB

  const size_t S_We1 = (size_t)2048 * 1536;
  const size_t S_We2 = (size_t)512 * 2048;
  const size_t S_z   = (size_t)4096 * 512;

  build_x<<<3072, 256, 0, stream>>>(s, c, x);
  transpose_cvt<<<dim3(32, 16, 1),  256, 0, stream>>>(Wg1, Wg1T, 1024, 2048, 0, 0);
  transpose_cvt<<<dim3(32, 24, 16), 256, 0, stream>>>(We1, We1T, 1536, 2048, S_We1, S_We1);
  // We2cat: [512 n][32768 k], per-expert k-offset 2048
  transpose_cvt<<<dim3(8, 32, 16),  256, 0, stream>>>(We2, We2cat, 32768, 512, S_We2, 2048);
  transpose_cvt<<<dim3(256, 8, 1),  256, 0, stream>>>(WA, WABT, 512, 16384, 0, 0);
  transpose_cvt<<<dim3(256, 8, 1),  256, 0, stream>>>(WB, WABT + (size_t)16384 * 512, 512, 16384, 0, 0);

  // gating: hg = relu(s @ Wg1 + bg1), then gates = softmax(hg @ Wg2 + bg2)
  gemm256p<0, 1><<<dim3(16, 8, 1), 512, 0, stream>>>(x, Wg1T, bg1, nullptr, hg,
      1024, 1536, 1024, 2048, 0, 0, 0, 0, nullptr);
  gating2_softmax<<<1024, 256, 0, stream>>>(hg, Wg2, bg2, gates);

  // expert-1 (all 16, one dispatch): h[r, e*2048+c] = g[r,e]*relu(x@We1[e]^T + be1[e])
  gemm256p<2, 1><<<dim3(16, 8, 16), 512, 0, stream>>>(x, We1T, be1, nullptr, h,
      1536, 1536, 1536, 32768, 0, S_We1, 2048, 2048, gates);

  // expert-2 as ONE GEMM K=32768, split-K x8 into zsplit (fp32 float4 stores)
  gemm256p<4, 0><<<dim3(2, 16, 8), 512, 0, stream>>>(h, We2cat, be2, nullptr, zsplit,
      4096, 32768, 32768, 512, 4096, 4096, 0, S_z, nullptr);

  // zb = bf16( sum_s zsplit[s] + gates @ be2 )
  reduce_z8<<<2048, 256, 0, stream>>>(zsplit, gates, be2, zb);

  // fused LoRA heads: C = zb @ [WA; WB]^T
  gemm256p<3, 1><<<dim3(16, 128, 1), 512, 0, stream>>>(zb, WABT, bA, bB, out,
      512, 512, 512, 16384, 0, 0, 0, (size_t)4096 * 16384, nullptr);
}